// Round 9
// baseline (83.395 us; speedup 1.0000x reference)
//
#include <hip/hip_runtime.h>

// IDW, POWER=2.0 -> w = 1/d2 (sqrt cancels). out = sum(w*v)/sum(w).
// B=2, P=131072, S=512.
// R9: SMEM station path (addrspace(4) + uniform index -> s_load into SGPRs;
//     zero vector-pipe cost) + GPT=1 so waves/SIMD doubles to 4. R5/R6/R8 all
//     plateaued at ~30us (2x the 15us VALU floor) regardless of station path:
//     at 2 waves/SIMD the per-body lgkmcnt latency (~150-300cyc) can't hide.
//     SMEM wait is pure latency (scalar pipe has spare issue), so 4-way TLP
//     covers it. Per-wave chunk cost: 31 plain + 1 rcp ~= 68 cyc; floor:
//     4 waves x 128 chunks x 68 / 2.4GHz ~= 14.6us.
// 4-way rcp combine: 1 v_rcp per 4 stations. EPS2 folded into the d2 fma
// chain (exact at d2==0: w -> 1/EPS^2 like ref).

#define BLOCK 256

typedef float v4f __attribute__((ext_vector_type(4)));
typedef const __attribute__((address_space(4))) v4f k_v4f;

__global__ __launch_bounds__(BLOCK) void idw_kernel(
    const float* __restrict__ station_coords,  // (B, S, 2)
    const float* __restrict__ station_values,  // (B, S)
    const float* __restrict__ grid_points,     // (B, P, 2)
    float* __restrict__ out,                   // (B, P)
    int P, int S) {

    const int b = blockIdx.y;

    // Wave-uniform station data through the scalar pipe:
    // coords: 2 stations per v4f (xA yA xB yB); values: 4 per v4f.
    k_v4f* sc4 = (k_v4f*)(station_coords + (size_t)b * S * 2);
    k_v4f* sv4 = (k_v4f*)(station_values + (size_t)b * S);

    // One point per thread; grid sized exactly.
    const int p = blockIdx.x * BLOCK + threadIdx.x;
    const float2 g = ((const float2*)grid_points)[(size_t)b * P + p];
    const float gx = g.x, gy = g.y;

    constexpr float EPS  = 1.1920928955078125e-07f;
    constexpr float EPS2 = EPS * EPS;

    float wsum = 0.0f, vsum = 0.0f;

#pragma unroll 4
    for (int k = 0; k < 512 / 4; ++k) {
        const v4f cAB = sc4[2 * k + 0];   // s_load_dwordx4 (uniform)
        const v4f cCD = sc4[2 * k + 1];
        const v4f vv  = sv4[k];

        // 4 stations (A,B,C,D): 31 plain VALU + 1 rcp.
        const float dxa = gx - cAB.x, dya = gy - cAB.y;
        const float a = fmaf(dxa, dxa, fmaf(dya, dya, EPS2));
        const float dxb = gx - cAB.z, dyb = gy - cAB.w;
        const float bq = fmaf(dxb, dxb, fmaf(dyb, dyb, EPS2));
        const float dxc = gx - cCD.x, dyc = gy - cCD.y;
        const float c = fmaf(dxc, dxc, fmaf(dyc, dyc, EPS2));
        const float dxd = gx - cCD.z, dyd = gy - cCD.w;
        const float d = fmaf(dxd, dxd, fmaf(dyd, dyd, EPS2));
        const float pab = a * bq, pcd = c * d;
        const float sab = a + bq, scd = c + d;
        const float nab = fmaf(vv.y, a, vv.x * bq);  // vB*a + vA*b
        const float ncd = fmaf(vv.w, c, vv.z * d);   // vD*c + vC*d
        const float r = __builtin_amdgcn_rcpf(pab * pcd);
        wsum = fmaf(fmaf(sab, pcd, scd * pab), r, wsum);
        vsum = fmaf(fmaf(nab, pcd, ncd * pab), r, vsum);
    }

    out[(size_t)b * P + p] = vsum / wsum;
}

extern "C" void kernel_launch(void* const* d_in, const int* in_sizes, int n_in,
                              void* d_out, int out_size, void* d_ws, size_t ws_size,
                              hipStream_t stream) {
    const float* station_coords = (const float*)d_in[0];
    const float* station_values = (const float*)d_in[1];
    const float* grid_points    = (const float*)d_in[2];
    float* out = (float*)d_out;

    const int B = 2;
    const int S = in_sizes[1] / B;   // 512
    const int P = out_size / B;      // 131072

    dim3 grid(P / BLOCK, B);  // 512 x 2 = 1024 blocks, 4/CU, 4 waves/SIMD
    dim3 block(BLOCK);
    idw_kernel<<<grid, block, 0, stream>>>(station_coords, station_values,
                                           grid_points, out, P, S);
}

// Round 10
// 82.657 us; speedup vs baseline: 1.0089x; 1.0089x over previous
//
#include <hip/hip_runtime.h>

// IDW, POWER=2.0 -> w = 1/d2 (sqrt cancels). out = sum(w*v)/sum(w).
// B=2, P=131072, S=512.
// R10: station-split teams. Block=256=4 waves; each wave = one team covering
//   the SAME 256 points (GPT=4: 64 lanes x 4 pts) but only 1/4 of stations
//   (128). Partials combined via LDS. Breaks the R1-R9 tension: GPT=4 fetch
//   economy (per-CU LDS pipe ~7.7us) AND 4 waves/SIMD for latency hiding
//   (1024 blocks = 4/CU). VALU floor ~14.1us; predict kernel ~17us.
// Quad math (proven R6-R9): 4-way rcp combine, 1 v_rcp per 4 stations;
// EPS2 folded into d2 fma chain (exact at d2==0: w -> 1/EPS^2 like ref).

#define BLOCK 256
#define S_MAX 512
#define TEAMS 4
#define S_PER_TEAM (S_MAX / TEAMS)   // 128
#define CHUNKS (S_PER_TEAM / 4)      // 32

__global__ __launch_bounds__(BLOCK) void idw_kernel(
    const float* __restrict__ station_coords,  // (B, S, 2)
    const float* __restrict__ station_values,  // (B, S)
    const float* __restrict__ grid_points,     // (B, P, 2)
    float* __restrict__ out,                   // (B, P)
    int P, int S) {

    __shared__ float  st[S_MAX * 3];            // 6 KB: {x,y,v} packed 12B
    __shared__ float2 part[TEAMS][BLOCK];       // 8 KB: per-team partials

    const int b = blockIdx.y;
    const float2* __restrict__ sc2 = (const float2*)(station_coords) + (size_t)b * S;
    const float*  __restrict__ svb = station_values + (size_t)b * S;

    for (int i = threadIdx.x; i < S; i += BLOCK) {
        const float2 c = sc2[i];
        st[3 * i + 0] = c.x;
        st[3 * i + 1] = c.y;
        st[3 * i + 2] = svb[i];
    }
    __syncthreads();

    const int team = threadIdx.x >> 6;   // wave id = station quarter
    const int lane = threadIdx.x & 63;

    // 4 consecutive points per lane; every team covers the same 256 points.
    const int pbase = blockIdx.x * BLOCK + 4 * lane;
    const float4* __restrict__ gp4 = (const float4*)(grid_points + (size_t)b * P * 2);
    const float4 gA = gp4[pbase / 2 + 0];  // x0 y0 x1 y1
    const float4 gB = gp4[pbase / 2 + 1];  // x2 y2 x3 y3
    const float gx0 = gA.x, gy0 = gA.y, gx1 = gA.z, gy1 = gA.w;
    const float gx2 = gB.x, gy2 = gB.y, gx3 = gB.z, gy3 = gB.w;

    constexpr float EPS  = 1.1920928955078125e-07f;
    constexpr float EPS2 = EPS * EPS;

    float ws0 = 0.f, vs0 = 0.f, ws1 = 0.f, vs1 = 0.f;
    float ws2 = 0.f, vs2 = 0.f, ws3 = 0.f, vs3 = 0.f;

    // 4 stations A,B,C,D vs one point: 29 plain VALU + 1 rcp.
    // f0 = Ax Ay Av Bx | f1 = By Bv Cx Cy | f2 = Cv Dx Dy Dv
    auto quad = [&](float gx, float gy, float& ws, float& vs,
                    const float4& f0, const float4& f1, const float4& f2) {
        const float dxa = gx - f0.x, dya = gy - f0.y;
        const float a = fmaf(dxa, dxa, fmaf(dya, dya, EPS2));
        const float dxb = gx - f0.w, dyb = gy - f1.x;
        const float bq = fmaf(dxb, dxb, fmaf(dyb, dyb, EPS2));
        const float dxc = gx - f1.z, dyc = gy - f1.w;
        const float c = fmaf(dxc, dxc, fmaf(dyc, dyc, EPS2));
        const float dxd = gx - f2.y, dyd = gy - f2.z;
        const float d = fmaf(dxd, dxd, fmaf(dyd, dyd, EPS2));
        const float pab = a * bq, pcd = c * d;
        const float sab = a + bq, scd = c + d;
        const float nab = fmaf(f1.y, a, f0.z * bq);  // vB*a + vA*b
        const float ncd = fmaf(f2.w, c, f2.x * d);   // vD*c + vC*d
        const float r = __builtin_amdgcn_rcpf(pab * pcd);
        ws = fmaf(fmaf(sab, pcd, scd * pab), r, ws);
        vs = fmaf(fmaf(nab, pcd, ncd * pab), r, vs);
    };

    // This team's 128 stations: float base offset 3*128*team.
    const float4* __restrict__ stt = (const float4*)(st + 3 * S_PER_TEAM * team);

#pragma unroll 4
    for (int k = 0; k < CHUNKS; ++k) {
        const float4 f0 = stt[3 * k + 0];
        const float4 f1 = stt[3 * k + 1];
        const float4 f2 = stt[3 * k + 2];
        quad(gx0, gy0, ws0, vs0, f0, f1, f2);
        quad(gx1, gy1, ws1, vs1, f0, f1, f2);
        quad(gx2, gy2, ws2, vs2, f0, f1, f2);
        quad(gx3, gy3, ws3, vs3, f0, f1, f2);
    }

    // Publish partials, then thread t reduces point t across the 4 teams.
    part[team][4 * lane + 0] = make_float2(ws0, vs0);
    part[team][4 * lane + 1] = make_float2(ws1, vs1);
    part[team][4 * lane + 2] = make_float2(ws2, vs2);
    part[team][4 * lane + 3] = make_float2(ws3, vs3);
    __syncthreads();

    const int t = threadIdx.x;
    const float2 a0 = part[0][t], a1 = part[1][t], a2 = part[2][t], a3 = part[3][t];
    const float W = (a0.x + a1.x) + (a2.x + a3.x);
    const float V = (a0.y + a1.y) + (a2.y + a3.y);
    out[(size_t)b * P + blockIdx.x * BLOCK + t] = V / W;
}

extern "C" void kernel_launch(void* const* d_in, const int* in_sizes, int n_in,
                              void* d_out, int out_size, void* d_ws, size_t ws_size,
                              hipStream_t stream) {
    const float* station_coords = (const float*)d_in[0];
    const float* station_values = (const float*)d_in[1];
    const float* grid_points    = (const float*)d_in[2];
    float* out = (float*)d_out;

    const int B = 2;
    const int S = in_sizes[1] / B;   // 512
    const int P = out_size / B;      // 131072

    dim3 grid(P / BLOCK, B);  // 512 x 2 = 1024 blocks = 4/CU, 4 waves/SIMD
    dim3 block(BLOCK);
    idw_kernel<<<grid, block, 0, stream>>>(station_coords, station_values,
                                           grid_points, out, P, S);
}